// Round 5
// baseline (222.922 us; speedup 1.0000x reference)
//
#include <hip/hip_runtime.h>

typedef __attribute__((ext_vector_type(8))) short short8;
typedef __attribute__((ext_vector_type(4))) float float4v;

__device__ __forceinline__ unsigned short f2bf(float f) {
  unsigned int u = __float_as_uint(f);
  u += 0x7fffu + ((u >> 16) & 1u);   // round-to-nearest-even
  return (unsigned short)(u >> 16);
}
__device__ __forceinline__ float bf2f(unsigned short h) {
  return __uint_as_float(((unsigned int)h) << 16);
}

// async global->LDS, 16 B per lane; LDS dest = wave-uniform base + lane*16
#define GLOBAL_LOAD_LDS16(gptr, lptr)                                          \
  __builtin_amdgcn_global_load_lds(                                            \
      (const __attribute__((address_space(1))) unsigned int*)(gptr),           \
      (__attribute__((address_space(3))) unsigned int*)(lptr), 16, 0, 0)

// ---------------- prep: w' = gamma*w -> bf16 [n][k'] + colsum + bias ----------
// k' = c*8 + i (i = di*4+hi*2+wi), k_orig = i*96 + c
__global__ __launch_bounds__(256)
void prep_kernel(const float* __restrict__ w_red, const float* __restrict__ gamma,
                 const float* __restrict__ beta, unsigned short* __restrict__ w_bf,
                 float* __restrict__ colsum, float* __restrict__ bias) {
  const int n = blockIdx.x;       // 0..191
  const int t = threadIdx.x;      // 0..255
  float cs = 0.f, bs = 0.f;
#pragma unroll
  for (int j = 0; j < 3; ++j) {
    int kp = j * 256 + t;                       // k' 0..767
    int ko = (kp & 7) * 96 + (kp >> 3);         // original k
    float w = w_red[(size_t)ko * 192 + n];
    unsigned short v = f2bf(gamma[ko] * w);
    w_bf[(size_t)n * 768 + kp] = v;
    cs += bf2f(v);
    bs += beta[ko] * w;
  }
#pragma unroll
  for (int off = 1; off < 64; off <<= 1) {
    cs += __shfl_xor(cs, off, 64);
    bs += __shfl_xor(bs, off, 64);
  }
  __shared__ float red[2][4];
  const int wave = t >> 6;
  if ((t & 63) == 0) { red[0][wave] = cs; red[1][wave] = bs; }
  __syncthreads();
  if (t == 0) {
    colsum[n] = red[0][0] + red[0][1] + red[0][2] + red[0][3];
    bias[n]   = red[1][0] + red[1][1] + red[1][2] + red[1][3];
  }
}

// ---------------- main: async-DMA stage -> convert+stats -> MFMA -> epilogue --
// block = 16 sites (half a W-row). grid = 2048.
__global__ __launch_bounds__(256, 2)
void pm_kernel(const float* __restrict__ x, const unsigned short* __restrict__ w_bf,
               const float* __restrict__ colsum, const float* __restrict__ bias,
               float* __restrict__ out) {
  __shared__ __align__(16) float LDSX[12288];           // 49152 B: 384 rows x 32 f32
  __shared__ __align__(16) unsigned short Y[16][792];   // 25344 B bf16, k'-permuted
  __shared__ float4 part[4][8];
  __shared__ float smu[16], srs[16];

  const int tid = threadIdx.x;
  const int bid = blockIdx.x;
  const int b  = bid >> 10;
  const int dz = (bid >> 6) & 15;
  const int hy = (bid >> 1) & 31;
  const int wh = bid & 1;

  const float* xb = x + (size_t)b * 12582912u + (size_t)dz * 8192u
                      + (size_t)hy * 128u + wh * 32;

  const int rr   = tid >> 3;     // 0..31: row within an it-chunk
  const int seg  = tid & 7;      // 16-B segment within the 128-B row
  const int wave = tid >> 6;

  // Stage: 12 fire-and-forget DMA loads per wave (zero VGPR destinations).
  // LDSX slot(lane) mirrors the DMA lane mapping: off = it*1024 + wave*256 + lane*4 floats.
#pragma unroll
  for (int it = 0; it < 12; ++it) {
    int r  = it * 32 + rr;               // r = c*4 + di*2 + hi
    int c  = r >> 2;
    int di = (r >> 1) & 1;
    int hi = r & 1;
    const float* gp = xb + (size_t)c * 131072u + di * 4096 + hi * 64 + seg * 4;
    float* lp = &LDSX[it * 1024 + wave * 256];   // wave-uniform base
    GLOBAL_LOAD_LDS16(gp, lp);
  }
  __syncthreads();   // drains vmcnt(0) then barrier: LDSX fully landed

  // Convert pass: each thread reads exactly its own DMA slots (b128),
  // converts to bf16 into Y[site][k'], fused LN stats for its 2 sites.
  const int wx0 = seg * 2;
  float sum0 = 0.f, sq0 = 0.f, sum1 = 0.f, sq1 = 0.f;
#pragma unroll
  for (int it = 0; it < 12; ++it) {
    int r  = it * 32 + rr;
    int c  = r >> 2;
    int di = (r >> 1) & 1;
    int hi = r & 1;
    float4 vv = *(const float4*)&LDSX[it * 1024 + rr * 32 + seg * 4];
    int k0 = c * 8 + di * 4 + hi * 2;
    unsigned int p01 = (unsigned int)f2bf(vv.x) | ((unsigned int)f2bf(vv.y) << 16);
    unsigned int p23 = (unsigned int)f2bf(vv.z) | ((unsigned int)f2bf(vv.w) << 16);
    *(unsigned int*)&Y[wx0][k0]     = p01;
    *(unsigned int*)&Y[wx0 + 1][k0] = p23;
    sum0 += vv.x + vv.y;  sq0 += vv.x * vv.x + vv.y * vv.y;
    sum1 += vv.z + vv.w;  sq1 += vv.z * vv.z + vv.w * vv.w;
  }
  const int lane = tid & 63;
#pragma unroll
  for (int off = 8; off < 64; off <<= 1) {   // combine lanes sharing lane&7
    sum0 += __shfl_xor(sum0, off, 64);  sq0 += __shfl_xor(sq0, off, 64);
    sum1 += __shfl_xor(sum1, off, 64);  sq1 += __shfl_xor(sq1, off, 64);
  }
  if (lane < 8) part[wave][lane] = make_float4(sum0, sq0, sum1, sq1);
  __syncthreads();   // Y + partials ready

  if (tid < 16) {
    int sg = tid >> 1, odd = tid & 1;
    float s = 0.f, q = 0.f;
#pragma unroll
    for (int w = 0; w < 4; ++w) {
      float4 p = part[w][sg];
      s += odd ? p.z : p.x;
      q += odd ? p.w : p.y;
    }
    float mu  = s * (1.f / 768.f);
    float var = q * (1.f / 768.f) - mu * mu;
    smu[tid] = mu;
    srs[tid] = rsqrtf(var + 1e-5f);
  }

  // GEMM: 16x192 = (16x768)@(768x192). A frags from Y (1 b128/kc), B rows from
  // global w_bf (L2-resident), depth-2 rolling prefetch, zero barriers.
  const int lrow = lane & 15;
  const int lq   = lane >> 4;
  const unsigned short* wrow[3];
#pragma unroll
  for (int t3 = 0; t3 < 3; ++t3)
    wrow[t3] = w_bf + (size_t)((wave * 3 + t3) * 16 + lrow) * 768 + lq * 8;

  short8 b0[3], b1[3];
#pragma unroll
  for (int t3 = 0; t3 < 3; ++t3) b0[t3] = *(const short8*)(wrow[t3]);
#pragma unroll
  for (int t3 = 0; t3 < 3; ++t3) b1[t3] = *(const short8*)(wrow[t3] + 32);

  float4v acc[3];
#pragma unroll
  for (int t3 = 0; t3 < 3; ++t3)
#pragma unroll
    for (int r = 0; r < 4; ++r) acc[t3][r] = 0.f;

  for (int kc = 0; kc < 24; ++kc) {
    int kn = (kc + 2 <= 23) ? kc + 2 : 23;
    short8 b2[3];
#pragma unroll
    for (int t3 = 0; t3 < 3; ++t3) b2[t3] = *(const short8*)(wrow[t3] + kn * 32);
    short8 a = *(const short8*)&Y[lrow][kc * 32 + lq * 8];
#pragma unroll
    for (int t3 = 0; t3 < 3; ++t3)
      acc[t3] = __builtin_amdgcn_mfma_f32_16x16x32_bf16(a, b0[t3], acc[t3], 0, 0, 0);
#pragma unroll
    for (int t3 = 0; t3 < 3; ++t3) { b0[t3] = b1[t3]; b1[t3] = b2[t3]; }
  }

  // Per-channel constants before the barrier.
  float cs_n[3], bi_n[3];
#pragma unroll
  for (int t3 = 0; t3 < 3; ++t3) {
    int ng = (wave * 3 + t3) * 16 + lrow;
    cs_n[t3] = colsum[ng];
    bi_n[t3] = bias[ng];
  }

  __syncthreads();   // A-frag reads done; Y region reusable as Cs
  float* Cs = (float*)&Y[0][0];   // 192 chans x stride 20 f32 = 15360 B
#pragma unroll
  for (int t3 = 0; t3 < 3; ++t3) {
    int ng = (wave * 3 + t3) * 16 + lrow;
#pragma unroll
    for (int r = 0; r < 4; ++r) {
      int m = lq * 4 + r;   // site
      float vv = srs[m] * (acc[t3][r] - smu[m] * cs_n[t3]) + bi_n[t3];
      Cs[ng * 20 + m] = vv;
    }
  }
  __syncthreads();

  float* ob = out + (size_t)b * 3145728u + (size_t)dz * 1024u
                  + (size_t)hy * 32u + wh * 16;
#pragma unroll
  for (int it = 0; it < 3; ++it) {
    int idx = it * 256 + tid;    // 0..767 float4 tasks
    int o  = idx >> 2;           // channel 0..191
    int wq = idx & 3;            // 4-float group within 16 sites
    float4 vv = *(const float4*)&Cs[o * 20 + wq * 4];
    *(float4*)(ob + (size_t)o * 16384u + wq * 4) = vv;
  }
}

extern "C" void kernel_launch(void* const* d_in, const int* in_sizes, int n_in,
                              void* d_out, int out_size, void* d_ws, size_t ws_size,
                              hipStream_t stream) {
  const float* x     = (const float*)d_in[0];
  const float* gamma = (const float*)d_in[1];
  const float* beta  = (const float*)d_in[2];
  const float* w_red = (const float*)d_in[3];
  float* out = (float*)d_out;

  unsigned short* w_bf = (unsigned short*)d_ws;            // 192*768*2 = 294912 B
  float* colsum = (float*)((char*)d_ws + 294912);          // 192 f32
  float* bias   = colsum + 192;                            // 192 f32

  prep_kernel<<<dim3(192), dim3(256), 0, stream>>>(w_red, gamma, beta, w_bf, colsum, bias);
  pm_kernel<<<dim3(2048), dim3(256), 0, stream>>>(x, w_bf, colsum, bias, out);
}